// Round 5
// baseline (554.008 us; speedup 1.0000x reference)
//
#include <hip/hip_runtime.h>
#include <math.h>

// Problem constants (fixed by the reference).
#define NU   100000      // N users
#define MI   50000       // M items
#define NEn  150000      // NE = N + M
#define Bp   131072      // batch pairs

#define GRID1 2048       // k_ent blocks (grid-stride, 8192 waves, 2 rows/iter)
#define GRID2 2048       // k_log blocks (grid-stride, 16384 half-wave groups)

// Native vector types (__builtin_nontemporal_* rejects struct float4).
typedef float    f4v __attribute__((ext_vector_type(4)));
typedef float    f2v __attribute__((ext_vector_type(2)));
typedef _Float16 h8v __attribute__((ext_vector_type(8)));   // 16 B of fp16
typedef _Float16 h4v __attribute__((ext_vector_type(4)));   // 8 B of fp16

// ---------------------------------------------------------------------------
// 64-lane wave reduction (gfx950 wave = 64).
__device__ __forceinline__ float wred(float v) {
#pragma unroll
    for (int m = 32; m > 0; m >>= 1) v += __shfl_xor(v, m, 64);
    return v;
}
// 32-lane (half-wave) reduction: xor masks 16..1 stay within each half.
__device__ __forceinline__ float hred(float v) {
#pragma unroll
    for (int m = 16; m > 0; m >>= 1) v += __shfl_xor(v, m, 64);
    return v;
}

// ---------------------------------------------------------------------------
// K1: entity reparam + per-row KL. Grid-stride, one wave per row, 2 rows per
// iteration for load ILP. NO histogram: cnt has been algebraically eliminated
// (see K2). Block 0 zeroes hdr and seeds out[Bp] with kl_global.
// Streaming inputs nontemporal; fp16 enth output left cache-resident for K2.
__global__ __launch_bounds__(256) void k_ent(
    const f4v* __restrict__ et,       // entity_table, NE x 2D (row = 128 f4v)
    const f4v* __restrict__ epse,     // eps_entity,   NE x D  (row = 64 f4v)
    const f2v* __restrict__ bt2,      // bias_table as float2 per row
    const f2v* __restrict__ epsb2,    // eps_bias as float2 per 2 rows
    const float* __restrict__ gbm,
    const float* __restrict__ gbs,
    h4v*  __restrict__ enth,          // out: entities_all fp16 (512 B rows); may be null
    f2v*  __restrict__ bia2,          // out: biases_all (paired rows)
    f2v*  __restrict__ klpe2,         // out: kl per row (paired rows)
    float* __restrict__ hdr,          // zeroed here (U,I,A,B accumulators)
    float* __restrict__ outkl)        // out[Bp] seeded with kl_global
{
    if (blockIdx.x == 0) {
        if (threadIdx.x < 4) hdr[threadIdx.x] = 0.f;
        if (threadIdx.x == 0) {
            float gm = gbm[0], gs = fabsf(gbs[0]);
            outkl[0] = 0.5f * (gs * gs + gm * gm - 1.0f) - __logf(gs);
        }
    }

    const int lane = threadIdx.x & 63;
    const int gwav = blockIdx.x * 4 + (threadIdx.x >> 6);
    const int step = GRID1 * 4 * 2;   // rows consumed per grid iteration

    for (int r0 = gwav * 2; r0 < NEn; r0 += step) {
        // rows r0, r0+1 (NEn even, r0 even -> r0+1 always valid)
        const f4v* ra = et + (size_t)r0 * 128;
        const f4v* rb = ra + 128;
        // issue all six 16B loads up front (independent -> pipelined)
        f4v mu0 = __builtin_nontemporal_load(ra + lane);
        f4v s40 = __builtin_nontemporal_load(ra + 64 + lane);
        f4v mu1 = __builtin_nontemporal_load(rb + lane);
        f4v s41 = __builtin_nontemporal_load(rb + 64 + lane);
        f4v ep0 = __builtin_nontemporal_load(epse + (size_t)r0 * 64 + lane);
        f4v ep1 = __builtin_nontemporal_load(epse + (size_t)r0 * 64 + 64 + lane);

        float ax0 = fabsf(s40.x), ay0 = fabsf(s40.y), az0 = fabsf(s40.z), aw0 = fabsf(s40.w);
        float ax1 = fabsf(s41.x), ay1 = fabsf(s41.y), az1 = fabsf(s41.z), aw1 = fabsf(s41.w);

        if (enth) {
            h4v o0, o1;
            o0.x = (_Float16)fmaf(ax0, ep0.x, mu0.x);
            o0.y = (_Float16)fmaf(ay0, ep0.y, mu0.y);
            o0.z = (_Float16)fmaf(az0, ep0.z, mu0.z);
            o0.w = (_Float16)fmaf(aw0, ep0.w, mu0.w);
            o1.x = (_Float16)fmaf(ax1, ep1.x, mu1.x);
            o1.y = (_Float16)fmaf(ay1, ep1.y, mu1.y);
            o1.z = (_Float16)fmaf(az1, ep1.z, mu1.z);
            o1.w = (_Float16)fmaf(aw1, ep1.w, mu1.w);
            enth[(size_t)r0 * 64 + lane]      = o0;   // temporal: cache-resident
            enth[(size_t)r0 * 64 + 64 + lane] = o1;
        }

        float kl0 = 0.5f * (ax0 * ax0 + mu0.x * mu0.x - 1.0f) - __logf(ax0)
                  + 0.5f * (ay0 * ay0 + mu0.y * mu0.y - 1.0f) - __logf(ay0)
                  + 0.5f * (az0 * az0 + mu0.z * mu0.z - 1.0f) - __logf(az0)
                  + 0.5f * (aw0 * aw0 + mu0.w * mu0.w - 1.0f) - __logf(aw0);
        float kl1 = 0.5f * (ax1 * ax1 + mu1.x * mu1.x - 1.0f) - __logf(ax1)
                  + 0.5f * (ay1 * ay1 + mu1.y * mu1.y - 1.0f) - __logf(ay1)
                  + 0.5f * (az1 * az1 + mu1.z * mu1.z - 1.0f) - __logf(az1)
                  + 0.5f * (aw1 * aw1 + mu1.w * mu1.w - 1.0f) - __logf(aw1);
        kl0 = wred(kl0);
        kl1 = wred(kl1);

        if (lane == 0) {
            f2v b0 = bt2[r0], b1 = bt2[r0 + 1];
            f2v eb = epsb2[r0 >> 1];
            float bs0 = fabsf(b0.y), bs1 = fabsf(b1.y);
            f2v bo, ko;
            bo.x = fmaf(bs0, eb.x, b0.x);
            bo.y = fmaf(bs1, eb.y, b1.x);
            ko.x = kl0 + 0.5f * (bs0 * bs0 + b0.x * b0.x - 1.0f) - __logf(bs0);
            ko.y = kl1 + 0.5f * (bs1 * bs1 + b1.x * b1.x - 1.0f) - __logf(bs1);
            bia2[r0 >> 1]  = bo;
            klpe2[r0 >> 1] = ko;
        }
    }
}

// ---------------------------------------------------------------------------
// K2: logits (fp16 gather, 2 pairs per wave / 16 B per lane, grid-stride)
// with cnt-free KL partials folded in. For each pair (u,v):
//   U += 1/nb[u];  I += 1/nb[v]
//   A += klpe[u]/nb[u] + (v==NU ? klpe[v]/nb[v] : 0)   (ids<=N quirk: e=NU)
//   B += (v>NU ? klpe[v]/nb[v] : 0)
// Per-thread accumulators -> wave reduce -> LDS -> 4 atomics/block onto hdr.
// k_fin turns hdr into kl_rescaled.
__global__ __launch_bounds__(256) void k_log(
    const int2* __restrict__ x2,
    const h8v* __restrict__ enth,     // row = 32 h8v (512 B); may be null
    const float* __restrict__ bia,
    const float* __restrict__ klpe,
    const int* __restrict__ nb,
    const float* __restrict__ gbm, const float* __restrict__ gbs,
    const float* __restrict__ epsg,
    float* __restrict__ hdr,
    float* __restrict__ out)
{
    const int lane = threadIdx.x & 63;
    const int sub  = lane & 31;                         // lane within half-wave
    const int grp  = (blockIdx.x * 4 + (threadIdx.x >> 6)) * 2 + (lane >> 5);
    const int ngrp = GRID2 * 4 * 2;                     // 16384 half-wave groups
    const float gb = fmaf(fabsf(gbs[0]), epsg[0], gbm[0]);
    const bool use_ent = (enth != nullptr);

    float uS = 0.f, iS = 0.f, aS = 0.f, bS = 0.f;

    for (int p = grp; p < Bp; p += ngrp) {
        int2 pr = x2[p];
        int u = pr.x, v = pr.y;
        if (use_ent) {
            float bu = bia[u];                          // prefetch with gathers
            float bv = bia[v];
            h8v a = enth[(size_t)u * 32 + sub];
            h8v b = enth[(size_t)v * 32 + sub];
            float d = 0.f;
#pragma unroll
            for (int i = 0; i < 8; ++i) d = fmaf((float)a[i], (float)b[i], d);
            d = hred(d);
            if (sub == 0)
                __builtin_nontemporal_store(gb + bu + bv + d, out + p);
        }
        if (sub == 0) {
            float rnu = 1.0f / (float)nb[u];
            float rnv = 1.0f / (float)nb[v];
            float au  = klpe[u] * rnu;
            float av  = klpe[v] * rnv;
            uS += rnu;
            iS += rnv;
            aS += au + ((v == NU) ? av : 0.f);
            bS += ((v > NU) ? av : 0.f);
        }
    }

    uS = wred(uS); iS = wred(iS); aS = wred(aS); bS = wred(bS);
    __shared__ float s[4][4];
    int wib = threadIdx.x >> 6;
    if (lane == 0) { s[wib][0] = uS; s[wib][1] = iS; s[wib][2] = aS; s[wib][3] = bS; }
    __syncthreads();
    if (threadIdx.x < 4) {
        float t = s[0][threadIdx.x] + s[1][threadIdx.x]
                + s[2][threadIdx.x] + s[3][threadIdx.x];
        if (t != 0.f) atomicAdd(hdr + threadIdx.x, t);
    }
}

// ---------------------------------------------------------------------------
// K3: finalize KL scalar. out[Bp] already holds kl_global (K1).
// hdr = {U, I, A, B};  kl_rescaled = N*A/U + M*B/I.
__global__ void k_fin(const float* __restrict__ hdr, float* __restrict__ outkl) {
    if (threadIdx.x == 0)
        outkl[0] += (float)NU * hdr[2] / hdr[0] + (float)MI * hdr[3] / hdr[1];
}

// ---------------------------------------------------------------------------
// Fallback gather (ws too small for fp16 ent — never expected, ws ~1.2 GB):
// recompute reparameterized rows in the gather, one pair per wave.
__global__ __launch_bounds__(256) void k_logits_rc(
    const int* __restrict__ x, const float4* __restrict__ et,
    const float4* __restrict__ epse, const float* __restrict__ bia,
    const float* __restrict__ gbm, const float* __restrict__ gbs,
    const float* __restrict__ epsg, float* __restrict__ out)
{
    int lane = threadIdx.x & 63;
    int p    = blockIdx.x * 4 + (threadIdx.x >> 6);
    int u = x[2 * p], v = x[2 * p + 1];
    const float4* ru = et + (size_t)u * 128;
    const float4* rv = et + (size_t)v * 128;
    float4 mu_u = ru[lane], s_u = ru[64 + lane], e_u = epse[(size_t)u * 64 + lane];
    float4 mu_v = rv[lane], s_v = rv[64 + lane], e_v = epse[(size_t)v * 64 + lane];
    float ax = fmaf(fabsf(s_u.x), e_u.x, mu_u.x), bx = fmaf(fabsf(s_v.x), e_v.x, mu_v.x);
    float ay = fmaf(fabsf(s_u.y), e_u.y, mu_u.y), by = fmaf(fabsf(s_v.y), e_v.y, mu_v.y);
    float az = fmaf(fabsf(s_u.z), e_u.z, mu_u.z), bz = fmaf(fabsf(s_v.z), e_v.z, mu_v.z);
    float aw = fmaf(fabsf(s_u.w), e_u.w, mu_u.w), bw = fmaf(fabsf(s_v.w), e_v.w, mu_v.w);
    float d = ax * bx + ay * by + az * bz + aw * bw;
    d = wred(d);
    if (lane == 0) {
        float gb = fmaf(fabsf(gbs[0]), epsg[0], gbm[0]);
        out[p] = gb + bia[u] + bia[v] + d;
    }
}

// ---------------------------------------------------------------------------
extern "C" void kernel_launch(void* const* d_in, const int* in_sizes, int n_in,
                              void* d_out, int out_size, void* d_ws, size_t ws_size,
                              hipStream_t stream)
{
    const int*   x    = (const int*)d_in[0];
    const float* bt   = (const float*)d_in[1];
    const float* et   = (const float*)d_in[2];
    const float* gbm  = (const float*)d_in[3];
    const float* gbs  = (const float*)d_in[4];
    const int*   nb   = (const int*)d_in[5];
    const float* epsb = (const float*)d_in[6];
    const float* epse = (const float*)d_in[7];
    const float* epsg = (const float*)d_in[8];
    float* out = (float*)d_out;   // [0..Bp) logits, [Bp] KL scalar

    char*  ws   = (char*)d_ws;
    float* hdr  = (float*)ws;                              // hdr[0..3] = U,I,A,B
    float* klpe = (float*)(ws + 64);                       // NE floats
    float* bia  = (float*)(ws + 64 + (size_t)NEn * 4);     // NE floats
    size_t entoff = 64 + (size_t)NEn * 8;                  // 16B-aligned (1200064)
    h4v* enth = nullptr;
    if (ws_size >= entoff + (size_t)NEn * 512)             // fp16 rows: 512 B each
        enth = (h4v*)(ws + entoff);

    // No memset: hdr zeroed inside k_ent (block 0), cnt eliminated entirely.

    // K1: entity reparam + KL, grid-stride, 2 rows/wave/iter.
    k_ent<<<GRID1, 256, 0, stream>>>(
        (const f4v*)et, (const f4v*)epse, (const f2v*)bt, (const f2v*)epsb,
        gbm, gbs, enth, (f2v*)bia, (f2v*)klpe, hdr, out + Bp);

    // K2: logits + cnt-free KL partials (U,I,A,B).
    k_log<<<GRID2, 256, 0, stream>>>(
        (const int2*)x, (const h8v*)enth, bia, klpe, nb,
        gbm, gbs, epsg, hdr, out);

    if (!enth)  // safety net; ws is ~1.2 GB in practice
        k_logits_rc<<<Bp / 4, 256, 0, stream>>>(x, (const float4*)et,
                                                (const float4*)epse, bia,
                                                gbm, gbs, epsg, out);

    // K3: finalize KL scalar.
    k_fin<<<1, 64, 0, stream>>>(hdr, out + Bp);
}

// Round 6
// 550.285 us; speedup vs baseline: 1.0068x; 1.0068x over previous
//
#include <hip/hip_runtime.h>
#include <math.h>

// Problem constants (fixed by the reference).
#define NU   100000      // N users
#define MI   50000       // M items
#define NEn  150000      // NE = N + M
#define Bp   131072      // batch pairs

// Native vector types (__builtin_nontemporal_* rejects struct float4).
typedef float    f4v __attribute__((ext_vector_type(4)));
typedef _Float16 h8v __attribute__((ext_vector_type(8)));   // 16 B of fp16
typedef _Float16 h4v __attribute__((ext_vector_type(4)));   // 8 B of fp16

// ---------------------------------------------------------------------------
// 64-lane wave reduction (gfx950 wave = 64).
__device__ __forceinline__ float wred(float v) {
#pragma unroll
    for (int m = 32; m > 0; m >>= 1) v += __shfl_xor(v, m, 64);
    return v;
}
// 32-lane (half-wave) reduction: xor masks 16..1 stay within each half.
__device__ __forceinline__ float hred(float v) {
#pragma unroll
    for (int m = 16; m > 0; m >>= 1) v += __shfl_xor(v, m, 64);
    return v;
}

// ---------------------------------------------------------------------------
// K1: entity reparam + per-row KL. ONE-SHOT: NEn/4 blocks, one wave per row
// (R4-verified geometry — no grid-stride, no unroll; R5's persistent loop
// regressed). No histogram: cnt is algebraically eliminated (see K2).
// Block 0 zeroes the 32x4 hdr slots and seeds out[Bp] with kl_global.
// Streaming inputs nontemporal; fp16 enth output left cache-resident for K2.
__global__ __launch_bounds__(256) void k_ent(
    const f4v* __restrict__ et,       // entity_table, NE x 2D (row = 128 f4v)
    const f4v* __restrict__ epse,     // eps_entity,   NE x D  (row = 64 f4v)
    const float* __restrict__ bt,     // bias_table,   NE x 2
    const float* __restrict__ epsb,   // eps_bias,     NE
    const float* __restrict__ gbm,
    const float* __restrict__ gbs,
    h4v*   __restrict__ enth,         // out: entities_all fp16 (512 B rows); may be null
    float* __restrict__ bia,          // out: biases_all
    float* __restrict__ klpe,         // out: kl_bias + kl_entity per row
    float* __restrict__ hdr,          // zeroed here: 32 slots x {U,I,A,B}
    float* __restrict__ outkl)        // out[Bp] seeded with kl_global
{
    if (blockIdx.x == 0) {
        if (threadIdx.x < 128) hdr[threadIdx.x] = 0.f;
        if (threadIdx.x == 0) {
            float gm = gbm[0], gs = fabsf(gbs[0]);
            outkl[0] = 0.5f * (gs * gs + gm * gm - 1.0f) - __logf(gs);
        }
    }

    int lane = threadIdx.x & 63;
    int e    = blockIdx.x * 4 + (threadIdx.x >> 6);

    const f4v* row = et + (size_t)e * 128;
    f4v mu = __builtin_nontemporal_load(row + lane);
    f4v s4 = __builtin_nontemporal_load(row + 64 + lane);
    f4v ep = __builtin_nontemporal_load(epse + (size_t)e * 64 + lane);
    float scx = fabsf(s4.x), scy = fabsf(s4.y), scz = fabsf(s4.z), scw = fabsf(s4.w);

    if (enth) {
        h4v oh;
        oh.x = (_Float16)fmaf(scx, ep.x, mu.x);
        oh.y = (_Float16)fmaf(scy, ep.y, mu.y);
        oh.z = (_Float16)fmaf(scz, ep.z, mu.z);
        oh.w = (_Float16)fmaf(scw, ep.w, mu.w);
        enth[(size_t)e * 64 + lane] = oh;   // temporal: want this cache-resident
    }

    float kl = 0.5f * (scx * scx + mu.x * mu.x - 1.0f) - __logf(scx)
             + 0.5f * (scy * scy + mu.y * mu.y - 1.0f) - __logf(scy)
             + 0.5f * (scz * scz + mu.z * mu.z - 1.0f) - __logf(scz)
             + 0.5f * (scw * scw + mu.w * mu.w - 1.0f) - __logf(scw);
    kl = wred(kl);

    if (lane == 0) {
        float bmu = bt[2 * e];
        float bsc = fabsf(bt[2 * e + 1]);
        bia[e]  = fmaf(bsc, epsb[e], bmu);
        klpe[e] = kl + 0.5f * (bsc * bsc + bmu * bmu - 1.0f) - __logf(bsc);
    }
}

// ---------------------------------------------------------------------------
// K2: logits (fp16 gather, 2 pairs per wave / 16 B per lane — R4-verified
// geometry) with cnt-free KL partials folded in. Per pair (u,v):
//   U += 1/nb[u];  I += 1/nb[v]
//   A += klpe[u]/nb[u] + (v==NU ? klpe[v]/nb[v] : 0)   (ids<=N quirk: e=NU)
//   B += (v>NU ? klpe[v]/nb[v] : 0)
// Partials -> wave reduce -> LDS -> 4 atomics/block onto hdr slot (block&31),
// spreading contention across 32 slots. k_fin folds the slots.
__global__ __launch_bounds__(256) void k_log(
    const int2* __restrict__ x2,
    const h8v* __restrict__ enth,     // row = 32 h8v (512 B); may be null
    const float* __restrict__ bia,
    const float* __restrict__ klpe,
    const int* __restrict__ nb,
    const float* __restrict__ gbm, const float* __restrict__ gbs,
    const float* __restrict__ epsg,
    float* __restrict__ hdr,
    float* __restrict__ out)
{
    const int lane = threadIdx.x & 63;
    const int sub  = lane & 31;                         // lane within half-wave
    const int p    = blockIdx.x * 8 + ((threadIdx.x >> 6) << 1) + (lane >> 5);
    const bool use_ent = (enth != nullptr);

    int2 pr = x2[p];
    int u = pr.x, v = pr.y;

    if (use_ent) {
        float bu = bia[u];                              // prefetch with gathers
        float bv = bia[v];
        h8v a = enth[(size_t)u * 32 + sub];
        h8v b = enth[(size_t)v * 32 + sub];
        float d = 0.f;
#pragma unroll
        for (int i = 0; i < 8; ++i) d = fmaf((float)a[i], (float)b[i], d);
        d = hred(d);
        if (sub == 0) {
            float gb = fmaf(fabsf(gbs[0]), epsg[0], gbm[0]);
            __builtin_nontemporal_store(gb + bu + bv + d, out + p);
        }
    }

    // ---- per-pair KL partials (one lane per half-wave) ----
    float uS = 0.f, iS = 0.f, aS = 0.f, bS = 0.f;
    if (sub == 0) {
        float rnu = 1.0f / (float)nb[u];
        float rnv = 1.0f / (float)nb[v];
        float au  = klpe[u] * rnu;
        float av  = klpe[v] * rnv;
        uS = rnu;
        iS = rnv;
        aS = au + ((v == NU) ? av : 0.f);
        bS = ((v > NU) ? av : 0.f);
    }
    uS = wred(uS); iS = wred(iS); aS = wred(aS); bS = wred(bS);

    __shared__ float s[4][4];
    int wib = threadIdx.x >> 6;
    if (lane == 0) { s[wib][0] = uS; s[wib][1] = iS; s[wib][2] = aS; s[wib][3] = bS; }
    __syncthreads();
    if (threadIdx.x < 4) {
        float t = s[0][threadIdx.x] + s[1][threadIdx.x]
                + s[2][threadIdx.x] + s[3][threadIdx.x];
        atomicAdd(hdr + (blockIdx.x & 31) * 4 + threadIdx.x, t);
    }
}

// ---------------------------------------------------------------------------
// K3: finalize KL scalar. out[Bp] already holds kl_global (K1).
// hdr = 32 slots of {U, I, A, B};  kl_rescaled = N*A/U + M*B/I.
__global__ void k_fin(const float* __restrict__ hdr, float* __restrict__ outkl) {
    if (threadIdx.x == 0) {
        float U = 0.f, I = 0.f, A = 0.f, Bv = 0.f;
#pragma unroll
        for (int i = 0; i < 32; ++i) {
            U  += hdr[i * 4 + 0];
            I  += hdr[i * 4 + 1];
            A  += hdr[i * 4 + 2];
            Bv += hdr[i * 4 + 3];
        }
        outkl[0] += (float)NU * A / U + (float)MI * Bv / I;
    }
}

// ---------------------------------------------------------------------------
// Fallback gather (ws too small for fp16 ent — never expected, ws ~1.2 GB):
// recompute reparameterized rows in the gather, one pair per wave.
__global__ __launch_bounds__(256) void k_logits_rc(
    const int* __restrict__ x, const float4* __restrict__ et,
    const float4* __restrict__ epse, const float* __restrict__ bia,
    const float* __restrict__ gbm, const float* __restrict__ gbs,
    const float* __restrict__ epsg, float* __restrict__ out)
{
    int lane = threadIdx.x & 63;
    int p    = blockIdx.x * 4 + (threadIdx.x >> 6);
    int u = x[2 * p], v = x[2 * p + 1];
    const float4* ru = et + (size_t)u * 128;
    const float4* rv = et + (size_t)v * 128;
    float4 mu_u = ru[lane], s_u = ru[64 + lane], e_u = epse[(size_t)u * 64 + lane];
    float4 mu_v = rv[lane], s_v = rv[64 + lane], e_v = epse[(size_t)v * 64 + lane];
    float ax = fmaf(fabsf(s_u.x), e_u.x, mu_u.x), bx = fmaf(fabsf(s_v.x), e_v.x, mu_v.x);
    float ay = fmaf(fabsf(s_u.y), e_u.y, mu_u.y), by = fmaf(fabsf(s_v.y), e_v.y, mu_v.y);
    float az = fmaf(fabsf(s_u.z), e_u.z, mu_u.z), bz = fmaf(fabsf(s_v.z), e_v.z, mu_v.z);
    float aw = fmaf(fabsf(s_u.w), e_u.w, mu_u.w), bw = fmaf(fabsf(s_v.w), e_v.w, mu_v.w);
    float d = ax * bx + ay * by + az * bz + aw * bw;
    d = wred(d);
    if (lane == 0) {
        float gb = fmaf(fabsf(gbs[0]), epsg[0], gbm[0]);
        out[p] = gb + bia[u] + bia[v] + d;
    }
}

// ---------------------------------------------------------------------------
extern "C" void kernel_launch(void* const* d_in, const int* in_sizes, int n_in,
                              void* d_out, int out_size, void* d_ws, size_t ws_size,
                              hipStream_t stream)
{
    const int*   x    = (const int*)d_in[0];
    const float* bt   = (const float*)d_in[1];
    const float* et   = (const float*)d_in[2];
    const float* gbm  = (const float*)d_in[3];
    const float* gbs  = (const float*)d_in[4];
    const int*   nb   = (const int*)d_in[5];
    const float* epsb = (const float*)d_in[6];
    const float* epse = (const float*)d_in[7];
    const float* epsg = (const float*)d_in[8];
    float* out = (float*)d_out;   // [0..Bp) logits, [Bp] KL scalar

    char*  ws   = (char*)d_ws;
    float* hdr  = (float*)ws;                              // 32 slots x {U,I,A,B} = 512 B
    float* klpe = (float*)(ws + 512);                      // NE floats
    float* bia  = (float*)(ws + 512 + (size_t)NEn * 4);    // NE floats
    size_t entoff = 512 + (size_t)NEn * 8;                 // 16B-aligned
    h4v* enth = nullptr;
    if (ws_size >= entoff + (size_t)NEn * 512)             // fp16 rows: 512 B each
        enth = (h4v*)(ws + entoff);

    // No memset: hdr zeroed inside k_ent (block 0); cnt eliminated entirely.

    // K1: entity reparam + KL, one-shot, one wave per row.
    k_ent<<<NEn / 4, 256, 0, stream>>>(
        (const f4v*)et, (const f4v*)epse, bt, epsb,
        gbm, gbs, enth, bia, klpe, hdr, out + Bp);

    // K2: logits + cnt-free KL partials, one-shot, 2 pairs per wave.
    k_log<<<Bp / 8, 256, 0, stream>>>(
        (const int2*)x, (const h8v*)enth, bia, klpe, nb,
        gbm, gbs, epsg, hdr, out);

    if (!enth)  // safety net; ws is ~1.2 GB in practice
        k_logits_rc<<<Bp / 4, 256, 0, stream>>>(x, (const float4*)et,
                                                (const float4*)epse, bia,
                                                gbm, gbs, epsg, out);

    // K3: finalize KL scalar.
    k_fin<<<1, 64, 0, stream>>>(hdr, out + Bp);
}

// Round 7
// 521.127 us; speedup vs baseline: 1.0631x; 1.0560x over previous
//
#include <hip/hip_runtime.h>
#include <math.h>

// Problem constants (fixed by the reference).
#define NU   100000      // N users
#define MI   50000       // M items
#define NEn  150000      // NE = N + M
#define Bp   131072      // batch pairs

#define PB   512         // partial-sum blocks in K2 (one pair per thread)
#define NSLOT 8          // hdr accumulator slots (atomics spread)

// Native vector types (__builtin_nontemporal_* rejects struct float4).
typedef float    f4v __attribute__((ext_vector_type(4)));
typedef _Float16 h8v __attribute__((ext_vector_type(8)));   // 16 B of fp16
typedef _Float16 h4v __attribute__((ext_vector_type(4)));   // 8 B of fp16

// ---------------------------------------------------------------------------
// 64-lane wave reduction (gfx950 wave = 64).
__device__ __forceinline__ float wred(float v) {
#pragma unroll
    for (int m = 32; m > 0; m >>= 1) v += __shfl_xor(v, m, 64);
    return v;
}
// 32-lane (half-wave) reduction: xor masks 16..1 stay within each half.
__device__ __forceinline__ float hred(float v) {
#pragma unroll
    for (int m = 16; m > 0; m >>= 1) v += __shfl_xor(v, m, 64);
    return v;
}

// ---------------------------------------------------------------------------
// K1: entity reparam + per-row KL. One-shot: NEn/4 blocks, one wave per row
// (R4-verified geometry). No histogram, no memset: cnt is algebraically
// eliminated (see K2 partials). Block 0 zeroes hdr slots + seeds kl_global.
// Streaming inputs nontemporal; fp16 enth output left cache-resident for K2.
__global__ __launch_bounds__(256) void k_ent(
    const f4v* __restrict__ et,       // entity_table, NE x 2D (row = 128 f4v)
    const f4v* __restrict__ epse,     // eps_entity,   NE x D  (row = 64 f4v)
    const float* __restrict__ bt,     // bias_table,   NE x 2
    const float* __restrict__ epsb,   // eps_bias,     NE
    const float* __restrict__ gbm,
    const float* __restrict__ gbs,
    h4v*   __restrict__ enth,         // out: entities_all fp16 (512 B rows); may be null
    float* __restrict__ bia,          // out: biases_all
    float* __restrict__ klpe,         // out: kl_bias + kl_entity per row
    float* __restrict__ hdr,          // zeroed here: NSLOT slots x {U,I,A,B}
    float* __restrict__ outkl)        // out[Bp] seeded with kl_global
{
    if (blockIdx.x == 0) {
        if (threadIdx.x < 4 * NSLOT) hdr[threadIdx.x] = 0.f;
        if (threadIdx.x == 0) {
            float gm = gbm[0], gs = fabsf(gbs[0]);
            outkl[0] = 0.5f * (gs * gs + gm * gm - 1.0f) - __logf(gs);
        }
    }

    int lane = threadIdx.x & 63;
    int e    = blockIdx.x * 4 + (threadIdx.x >> 6);

    const f4v* row = et + (size_t)e * 128;
    f4v mu = __builtin_nontemporal_load(row + lane);
    f4v s4 = __builtin_nontemporal_load(row + 64 + lane);
    f4v ep = __builtin_nontemporal_load(epse + (size_t)e * 64 + lane);
    float scx = fabsf(s4.x), scy = fabsf(s4.y), scz = fabsf(s4.z), scw = fabsf(s4.w);

    if (enth) {
        h4v oh;
        oh.x = (_Float16)fmaf(scx, ep.x, mu.x);
        oh.y = (_Float16)fmaf(scy, ep.y, mu.y);
        oh.z = (_Float16)fmaf(scz, ep.z, mu.z);
        oh.w = (_Float16)fmaf(scw, ep.w, mu.w);
        enth[(size_t)e * 64 + lane] = oh;   // temporal: want this cache-resident
    }

    float kl = 0.5f * (scx * scx + mu.x * mu.x - 1.0f) - __logf(scx)
             + 0.5f * (scy * scy + mu.y * mu.y - 1.0f) - __logf(scy)
             + 0.5f * (scz * scz + mu.z * mu.z - 1.0f) - __logf(scz)
             + 0.5f * (scw * scw + mu.w * mu.w - 1.0f) - __logf(scw);
    kl = wred(kl);

    if (lane == 0) {
        float bmu = bt[2 * e];
        float bsc = fabsf(bt[2 * e + 1]);
        bia[e]  = fmaf(bsc, epsb[e], bmu);
        klpe[e] = kl + 0.5f * (bsc * bsc + bmu * bmu - 1.0f) - __logf(bsc);
    }
}

// ---------------------------------------------------------------------------
// K2: KL partial sums over the BATCH (blocks [0,PB), one pair per thread)
// CONCURRENT with logits (blocks [PB, PB+Bp/8), fp16 gather, 2 pairs per
// wave / 16 B per lane — exact R4-verified logits shape, no added work).
//
// cnt-free algebra (verified R5/R6): per pair (u,v), u in [0,N), v in [N,NE):
//   U += 1/nb[u];  I += 1/nb[v]
//   A += klpe[u]/nb[u] + (v==NU ? klpe[v]/nb[v] : 0)   (ids<=N quirk: e=N)
//   B += (v>NU  ? klpe[v]/nb[v] : 0)
// kl_rescaled = N*A/U + M*B/I (finalized by K3). Partial blocks: 4 wave-
// reductions -> LDS -> 4 atomics/block spread over NSLOT hdr slots
// (512/NSLOT = 64 atomics per address — below R4's verified 586).
__global__ __launch_bounds__(256) void k_log(
    const int2* __restrict__ x2,
    const h8v* __restrict__ enth,     // row = 32 h8v (512 B); may be null
    const float* __restrict__ bia,
    const float* __restrict__ klpe,
    const int* __restrict__ nb,
    const float* __restrict__ gbm, const float* __restrict__ gbs,
    const float* __restrict__ epsg,
    float* __restrict__ hdr,
    float* __restrict__ out)
{
    if (blockIdx.x < PB) {
        // ---- partials part: one pair per thread, coalesced x2 read ----
        int p = blockIdx.x * 256 + threadIdx.x;       // PB*256 == Bp exactly
        int2 pr = x2[p];
        int u = pr.x, v = pr.y;
        float rnu = 1.0f / (float)nb[u];
        float rnv = 1.0f / (float)nb[v];
        float au  = klpe[u] * rnu;
        float av  = klpe[v] * rnv;
        float uS = rnu;
        float iS = rnv;
        float aS = au + ((v == NU) ? av : 0.f);
        float bS = ((v > NU) ? av : 0.f);

        uS = wred(uS); iS = wred(iS); aS = wred(aS); bS = wred(bS);
        __shared__ float s[4][4];
        int wib = threadIdx.x >> 6;
        if ((threadIdx.x & 63) == 0) {
            s[wib][0] = uS; s[wib][1] = iS; s[wib][2] = aS; s[wib][3] = bS;
        }
        __syncthreads();
        if (threadIdx.x < 4) {
            float t = s[0][threadIdx.x] + s[1][threadIdx.x]
                    + s[2][threadIdx.x] + s[3][threadIdx.x];
            atomicAdd(hdr + (blockIdx.x & (NSLOT - 1)) * 4 + threadIdx.x, t);
        }
        return;
    }

    // ---- logits part (exact R4-verified shape) ----
    int lane = threadIdx.x & 63;
    int sub  = lane & 31;                      // lane within half-wave
    int p    = (blockIdx.x - PB) * 8 + ((threadIdx.x >> 6) << 1) + (lane >> 5);
    int2 pr = x2[p];
    int u = pr.x, v = pr.y;
    float bu = bia[u];                         // prefetch: overlaps the gathers
    float bv = bia[v];
    h8v a = enth[(size_t)u * 32 + sub];
    h8v b = enth[(size_t)v * 32 + sub];
    float d = 0.f;
#pragma unroll
    for (int i = 0; i < 8; ++i) d = fmaf((float)a[i], (float)b[i], d);
    d = hred(d);
    if (sub == 0) {
        float gb = fmaf(fabsf(gbs[0]), epsg[0], gbm[0]);
        __builtin_nontemporal_store(gb + bu + bv + d, out + p);
    }
}

// ---------------------------------------------------------------------------
// K3: finalize KL scalar. out[Bp] already holds kl_global (K1).
// hdr = NSLOT slots of {U, I, A, B};  kl_rescaled = N*A/U + M*B/I.
__global__ void k_fin(const float* __restrict__ hdr, float* __restrict__ outkl) {
    if (threadIdx.x == 0) {
        float U = 0.f, I = 0.f, A = 0.f, Bv = 0.f;
#pragma unroll
        for (int i = 0; i < NSLOT; ++i) {
            U  += hdr[i * 4 + 0];
            I  += hdr[i * 4 + 1];
            A  += hdr[i * 4 + 2];
            Bv += hdr[i * 4 + 3];
        }
        outkl[0] += (float)NU * A / U + (float)MI * Bv / I;
    }
}

// ---------------------------------------------------------------------------
// Fallback gather (ws too small for fp16 ent — never expected, ws ~1.2 GB):
// recompute reparameterized rows in the gather, one pair per wave.
__global__ __launch_bounds__(256) void k_logits_rc(
    const int* __restrict__ x, const float4* __restrict__ et,
    const float4* __restrict__ epse, const float* __restrict__ bia,
    const float* __restrict__ gbm, const float* __restrict__ gbs,
    const float* __restrict__ epsg, float* __restrict__ out)
{
    int lane = threadIdx.x & 63;
    int p    = blockIdx.x * 4 + (threadIdx.x >> 6);
    int u = x[2 * p], v = x[2 * p + 1];
    const float4* ru = et + (size_t)u * 128;
    const float4* rv = et + (size_t)v * 128;
    float4 mu_u = ru[lane], s_u = ru[64 + lane], e_u = epse[(size_t)u * 64 + lane];
    float4 mu_v = rv[lane], s_v = rv[64 + lane], e_v = epse[(size_t)v * 64 + lane];
    float ax = fmaf(fabsf(s_u.x), e_u.x, mu_u.x), bx = fmaf(fabsf(s_v.x), e_v.x, mu_v.x);
    float ay = fmaf(fabsf(s_u.y), e_u.y, mu_u.y), by = fmaf(fabsf(s_v.y), e_v.y, mu_v.y);
    float az = fmaf(fabsf(s_u.z), e_u.z, mu_u.z), bz = fmaf(fabsf(s_v.z), e_v.z, mu_v.z);
    float aw = fmaf(fabsf(s_u.w), e_u.w, mu_u.w), bw = fmaf(fabsf(s_v.w), e_v.w, mu_v.w);
    float d = ax * bx + ay * by + az * bz + aw * bw;
    d = wred(d);
    if (lane == 0) {
        float gb = fmaf(fabsf(gbs[0]), epsg[0], gbm[0]);
        out[p] = gb + bia[u] + bia[v] + d;
    }
}

// ---------------------------------------------------------------------------
extern "C" void kernel_launch(void* const* d_in, const int* in_sizes, int n_in,
                              void* d_out, int out_size, void* d_ws, size_t ws_size,
                              hipStream_t stream)
{
    const int*   x    = (const int*)d_in[0];
    const float* bt   = (const float*)d_in[1];
    const float* et   = (const float*)d_in[2];
    const float* gbm  = (const float*)d_in[3];
    const float* gbs  = (const float*)d_in[4];
    const int*   nb   = (const int*)d_in[5];
    const float* epsb = (const float*)d_in[6];
    const float* epse = (const float*)d_in[7];
    const float* epsg = (const float*)d_in[8];
    float* out = (float*)d_out;   // [0..Bp) logits, [Bp] KL scalar

    char*  ws   = (char*)d_ws;
    float* hdr  = (float*)ws;                              // NSLOT x {U,I,A,B}
    float* klpe = (float*)(ws + 512);                      // NE floats
    float* bia  = (float*)(ws + 512 + (size_t)NEn * 4);    // NE floats
    size_t entoff = 512 + (size_t)NEn * 8;                 // 16B-aligned
    h4v* enth = nullptr;
    if (ws_size >= entoff + (size_t)NEn * 512)             // fp16 rows: 512 B each
        enth = (h4v*)(ws + entoff);

    // No memset: hdr zeroed inside k_ent (block 0); cnt eliminated entirely.

    // K1: entity reparam + KL, one-shot, one wave per row.
    k_ent<<<NEn / 4, 256, 0, stream>>>(
        (const f4v*)et, (const f4v*)epse, bt, epsb,
        gbm, gbs, enth, bia, klpe, hdr, out + Bp);

    // K2: batch partials (PB blocks) || logits (Bp/8 blocks, R4 shape).
    if (enth) {
        k_log<<<PB + Bp / 8, 256, 0, stream>>>(
            (const int2*)x, (const h8v*)enth, bia, klpe, nb,
            gbm, gbs, epsg, hdr, out);
    } else {
        k_log<<<PB, 256, 0, stream>>>(         // partials only
            (const int2*)x, nullptr, bia, klpe, nb,
            gbm, gbs, epsg, hdr, out);
        k_logits_rc<<<Bp / 4, 256, 0, stream>>>(x, (const float4*)et,
                                                (const float4*)epse, bia,
                                                gbm, gbs, epsg, out);
    }

    // K3: finalize KL scalar.
    k_fin<<<1, 64, 0, stream>>>(hdr, out + Bp);
}